// Round 13
// baseline (326.103 us; speedup 1.0000x reference)
//
#include <hip/hip_runtime.h>
#include <math.h>

#define NN 20000     // nodes
#define NE 320000    // edges
#define HD 256       // hidden dim
#define EDIM 64      // edge feature dim
#define DIN 576      // 2H + ED
#define ASTRIDE 264  // LDS row stride in halves

typedef __attribute__((ext_vector_type(4))) _Float16 h4;
typedef __attribute__((ext_vector_type(8))) _Float16 h8;
typedef __attribute__((ext_vector_type(4))) float f32x4;

// fragment order: frag(cf, ks, l, j) = W[cf*16 + (l&15)][ks*32 + (l>>4)*8 + j]
__device__ _Float16 g_W1cf[16 * 2 * 64 * 8];    // W1 eattr part
__device__ _Float16 g_W12f[32 * 8 * 64 * 8];    // [W1a;W1b] for pre kernel (B-operand)
__device__ _Float16 g_Wrzf[32 * 16 * 64 * 8];   // GRU r,z: K=512 = [Wfold | W_hh]
__device__ _Float16 g_Wnxf[16 * 8 * 64 * 8];    // GRU n-gate, S side (Wfold rows 512..767)
__device__ _Float16 g_Wnhf[16 * 8 * 64 * 8];    // GRU n-gate, h side (W_hh rows 512..767)
__device__ float    g_Wib2[768];                // W_ih @ b2
__device__ _Float16 g_pre[(size_t)NN * 512];    // [node][pre1(256) | pre2(256)]
__device__ _Float16 g_hf[(size_t)NN * 256];     // h as fp16
__device__ int      g_rowptr[NN + 1];
__device__ int      g_cursor[NN];
__device__ int      g_perm[NE];                 // sorted position -> edge id
__device__ int      g_prow[NE];                 // sorted position -> dest node
__device__ int      g_pcol[NE];                 // sorted position -> source node

__device__ __forceinline__ h4 f2h4(float4 v) {
  return (h4){(_Float16)v.x, (_Float16)v.y, (_Float16)v.z, (_Float16)v.w};
}
__device__ __forceinline__ h8 f2h8(float4 a, float4 b) {
  return (h8){(_Float16)a.x, (_Float16)a.y, (_Float16)a.z, (_Float16)a.w,
              (_Float16)b.x, (_Float16)b.y, (_Float16)b.z, (_Float16)b.w};
}

// -------------------- merged weight repack + fold --------------------
__global__ __launch_bounds__(256) void cvtfold_kernel(
    const float* __restrict__ W1, const float* __restrict__ W_hh,
    const float* __restrict__ W_ih, const float* __restrict__ W2,
    const float* __restrict__ b2)
{
  const int bid = blockIdx.x;
  if (bid < 768) {
    const int r = bid, c = threadIdx.x;
    const float* wr = W_ih + (size_t)r * HD;
    float acc = 0.f;
    for (int m = 0; m < HD; ++m) acc += wr[m] * W2[(size_t)m * HD + c];
    const int ks = c >> 5, lg = (c >> 3) & 3, j = c & 7;
    const int l = lg * 16 + (r & 15);
    if (r < 512) {
      const int cf = (r < 256) ? (r >> 4) : (16 + ((r - 256) >> 4));
      g_Wrzf[(size_t)((cf * 16 + ks) * 64 + l) * 8 + j] = (_Float16)acc;
    } else {
      const int cf = (r - 512) >> 4;
      g_Wnxf[(size_t)((cf * 8 + ks) * 64 + l) * 8 + j] = (_Float16)acc;
    }
    if (c == 0) {
      float a2 = 0.f;
      for (int m = 0; m < HD; ++m) a2 += wr[m] * b2[m];
      g_Wib2[r] = a2;
    }
    return;
  }
  const int idx = (bid - 768) * 256 + threadIdx.x;
  const int g = idx >> 6, l = idx & 63;
  const int r16 = l & 15, koff = (l >> 4) * 8;
  const float* src; _Float16* dst;
  if (g < 32) {                                   // W1cf: cf<16, ks<2 (k = 512+...)
    const int cf = g >> 1, ks = g & 1;
    src = &W1[(size_t)(cf * 16 + r16) * DIN + 512 + ks * 32 + koff];
    dst = &g_W1cf[(size_t)(cf * 2 + ks) * 512 + l * 8];
  } else if (g < 288) {                           // W12f: cf<32, ks<8
    const int gg = g - 32, cf = gg >> 3, ks = gg & 7;
    src = (cf < 16) ? &W1[(size_t)(cf * 16 + r16) * DIN + ks * 32 + koff]
                    : &W1[(size_t)((cf - 16) * 16 + r16) * DIN + 256 + ks * 32 + koff];
    dst = &g_W12f[(size_t)(cf * 8 + ks) * 512 + l * 8];
  } else if (g < 544) {                           // Wrzf ks in [8,16): W_hh r,z rows
    const int gg = g - 288, cf = gg >> 3, ks = 8 + (gg & 7);
    const int row = (cf < 16) ? cf * 16 + r16 : 256 + (cf - 16) * 16 + r16;
    src = &W_hh[(size_t)row * HD + (ks - 8) * 32 + koff];
    dst = &g_Wrzf[(size_t)(cf * 16 + ks) * 512 + l * 8];
  } else {                                        // Wnhf: W_hh rows 512..767
    const int gg = g - 544, cf = gg >> 3, ks = gg & 7;
    src = &W_hh[(size_t)(512 + cf * 16 + r16) * HD + ks * 32 + koff];
    dst = &g_Wnhf[(size_t)(cf * 8 + ks) * 512 + l * 8];
  }
#pragma unroll
  for (int j = 0; j < 8; ++j) dst[j] = (_Float16)src[j];
}

// -------------------- pre kernel (+ edge histogram): pre12 = h @ [W1a|W1b]^T ----
#define PSTR 264
__global__ __launch_bounds__(256, 4) void pre_kernel(const float* __restrict__ h,
                                                     const int* __restrict__ ei,
                                                     int* __restrict__ deg) {
  __shared__ _Float16 A[32 * PSTR];   // 16.9 KB
  const int t = threadIdx.x, w = t >> 6, l = t & 63;
  const int l15 = l & 15, lg = l >> 4;
  const int nb = blockIdx.x * 32;

  {
    const int gid = blockIdx.x * 256 + t;
    atomicAdd(&deg[ei[gid]], 1);
    atomicAdd(&deg[ei[gid + NE / 2]], 1);
  }

  const int row = t >> 3, c8 = t & 7;
#pragma unroll
  for (int i = 0; i < 8; ++i) {
    const int col4 = c8 + i * 8;
    float4 v = ((const float4*)(h + (size_t)(nb + row) * HD))[col4];
    const h4 x = f2h4(v);
    *(h4*)&A[row * PSTR + col4 * 4] = x;
    *(h4*)&g_hf[(size_t)(nb + row) * 256 + col4 * 4] = x;
  }
  __syncthreads();

  f32x4 acc[2][8];
#pragma unroll
  for (int m = 0; m < 2; ++m)
#pragma unroll
    for (int n = 0; n < 8; ++n) acc[m][n] = (f32x4){0.f, 0.f, 0.f, 0.f};

  for (int ks = 0; ks < 8; ++ks) {
    h8 a[2];
#pragma unroll
    for (int m = 0; m < 2; ++m)
      a[m] = *(const h8*)&A[(m * 16 + l15) * PSTR + ks * 32 + lg * 8];
#pragma unroll
    for (int n = 0; n < 8; ++n) {
      const h8 b = *(const h8*)&g_W12f[(size_t)((w * 8 + n) * 8 + ks) * 512 + l * 8];
#pragma unroll
      for (int m = 0; m < 2; ++m)
        acc[m][n] = __builtin_amdgcn_mfma_f32_16x16x32_f16(a[m], b, acc[m][n], 0, 0, 0);
    }
  }

#pragma unroll
  for (int m = 0; m < 2; ++m)
#pragma unroll
    for (int n = 0; n < 8; ++n) {
      const int col = w * 128 + n * 16 + l15;
#pragma unroll
      for (int r = 0; r < 4; ++r)
        g_pre[(size_t)(nb + m * 16 + lg * 4 + r) * 512 + col] = (_Float16)acc[m][n][r];
    }
}

// -------------------- CSR build: scan -> scatter --------------------
__global__ __launch_bounds__(512) void scan_kernel(const int* __restrict__ deg) {
  __shared__ int part[512];
  const int t = threadIdx.x;
  const int base = t * 40;
  int loc[40];
  int s = 0;
#pragma unroll
  for (int i = 0; i < 40; ++i) {
    const int idx = base + i;
    const int d = (idx < NN) ? deg[idx] : 0;
    loc[i] = s; s += d;
  }
  part[t] = s;
  __syncthreads();
  for (int off = 1; off < 512; off <<= 1) {
    const int v = (t >= off) ? part[t - off] : 0;
    __syncthreads();
    part[t] += v;
    __syncthreads();
  }
  const int pre = (t == 0) ? 0 : part[t - 1];
#pragma unroll
  for (int i = 0; i < 40; ++i) {
    const int idx = base + i;
    if (idx < NN) { const int v = pre + loc[i]; g_rowptr[idx] = v; g_cursor[idx] = v; }
  }
  if (t == 511) g_rowptr[NN] = part[511];
}

__global__ __launch_bounds__(256) void scatter_kernel(const int* __restrict__ ei) {
  const int e = blockIdx.x * 256 + threadIdx.x;
  if (e < NE) {
    const int r = ei[e];
    const int p = atomicAdd(&g_cursor[r], 1);
    g_perm[p] = e;
    g_prow[p] = r;
    g_pcol[p] = ei[NE + e];
  }
}

// -------------------- aggmsg kernel: fused eattr-GEMM + segmented relu-sum ----
// Block = 64 SORTED positions. Phase 1: MFMA (A gathered from eattr[perm[p]]).
// Phase 2: LDS transpose. Phase 3: per-wave 16-row walk with register
// accumulation per dest segment, f32 atomic flush into S32. g_msg eliminated.
__global__ __launch_bounds__(256, 4) void aggmsg_kernel(const float* __restrict__ eattr,
                                                        const float* __restrict__ b1,
                                                        float* __restrict__ S32) {
  __shared__ _Float16 T[64 * ASTRIDE];   // 33.8 KB
  const int t = threadIdx.x, w = t >> 6, l = t & 63;
  const int l15 = l & 15, lg = l >> 4;
  const int p0 = blockIdx.x * 64;

  // per-lane edge ids for the A-operand rows (16 rows per m)
  int pe[4];
#pragma unroll
  for (int m = 0; m < 4; ++m) pe[m] = g_perm[p0 + m * 16 + l15];

  f32x4 acc[4][4];
#pragma unroll
  for (int m = 0; m < 4; ++m)
#pragma unroll
    for (int n = 0; n < 4; ++n) acc[m][n] = (f32x4){0.f, 0.f, 0.f, 0.f};

#pragma unroll
  for (int ks = 0; ks < 2; ++ks) {
    h8 a[4], b[4];
#pragma unroll
    for (int m = 0; m < 4; ++m) {
      const float* ep = eattr + (size_t)pe[m] * EDIM + ks * 32 + lg * 8;
      a[m] = f2h8(((const float4*)ep)[0], ((const float4*)ep)[1]);
    }
#pragma unroll
    for (int n = 0; n < 4; ++n)
      b[n] = *(const h8*)&g_W1cf[(size_t)((w * 4 + n) * 2 + ks) * 512 + l * 8];
#pragma unroll
    for (int m = 0; m < 4; ++m)
#pragma unroll
      for (int n = 0; n < 4; ++n)
        acc[m][n] = __builtin_amdgcn_mfma_f32_16x16x32_f16(a[m], b[n], acc[m][n], 0, 0, 0);
  }

#pragma unroll
  for (int m = 0; m < 4; ++m)
#pragma unroll
    for (int n = 0; n < 4; ++n)
#pragma unroll
      for (int r = 0; r < 4; ++r)
        T[(m * 16 + lg * 4 + r) * ASTRIDE + w * 64 + n * 16 + l15] = (_Float16)acc[m][n][r];
  __syncthreads();

  // ---- phase 3: segmented accumulate over this wave's 16 sorted rows ----
  const f32x4 b1v = *(const f32x4*)&b1[l * 4];
  int cur = -1;
  f32x4 sum = (f32x4){0.f, 0.f, 0.f, 0.f};
#pragma unroll
  for (int i = 0; i < 16; ++i) {
    const int p = p0 + w * 16 + i;
    const int node = g_prow[p];          // wave-uniform
    const int src  = g_pcol[p];          // wave-uniform
    const h4 tt = *(const h4*)&T[(w * 16 + i) * ASTRIDE + l * 4];
    const h4 q1 = *(const h4*)&g_pre[(size_t)node * 512 + l * 4];
    const h4 q2 = *(const h4*)&g_pre[(size_t)src * 512 + 256 + l * 4];
    f32x4 v;
#pragma unroll
    for (int r = 0; r < 4; ++r) {
      float x = (float)tt[r] + (float)q1[r] + (float)q2[r] + b1v[r];
      v[r] = x > 0.f ? x : 0.f;
    }
    if (node != cur) {
      if (cur >= 0) {
#pragma unroll
        for (int r = 0; r < 4; ++r) unsafeAtomicAdd(&S32[(size_t)cur * HD + l * 4 + r], sum[r]);
      }
      cur = node; sum = v;
    } else {
#pragma unroll
      for (int r = 0; r < 4; ++r) sum[r] += v[r];
    }
  }
#pragma unroll
  for (int r = 0; r < 4; ++r) unsafeAtomicAdd(&S32[(size_t)cur * HD + l * 4 + r], sum[r]);
}

// -------------------- node kernel: LDS-free streaming GEMM (S from f32) ----
__global__ __launch_bounds__(256, 2) void node_kernel(
    const float* __restrict__ S32,
    const float* __restrict__ b_ih, const float* __restrict__ b_hh,
    float* __restrict__ out)
{
  const int bid = blockIdx.x;
  const int cf = bid & 3, rng = bid >> 2;
  const int t = threadIdx.x, w = t >> 6, l = t & 63;
  const int l15 = l & 15, lg = l >> 4;
  const int nb = rng * 64;
  const int cf0 = cf * 4;
  int na = nb + w * 16 + l15; if (na >= NN) na = NN - 1;

  f32x4 ar[4], az[4], ax[4], ah[4];
#pragma unroll
  for (int n = 0; n < 4; ++n) {
    ar[n] = (f32x4){0.f, 0.f, 0.f, 0.f}; az[n] = (f32x4){0.f, 0.f, 0.f, 0.f};
    ax[n] = (f32x4){0.f, 0.f, 0.f, 0.f}; ah[n] = (f32x4){0.f, 0.f, 0.f, 0.f};
  }

  const float* aS = &S32[(size_t)na * 256 + lg * 8];
  const _Float16* aH = &g_hf[(size_t)na * 256 + lg * 8];

  // ---- S side ----
#pragma unroll
  for (int ks = 0; ks < 8; ++ks) {
    const float4 s0 = ((const float4*)&aS[ks * 32])[0];
    const float4 s1 = ((const float4*)&aS[ks * 32])[1];
    const h8 a = f2h8(s0, s1);
    h8 br[4], bz[4], bn[4];
#pragma unroll
    for (int n = 0; n < 4; ++n) {
      br[n] = *(const h8*)&g_Wrzf[(size_t)(((cf0 + n) * 16 + ks) * 64 + l) * 8];
      bz[n] = *(const h8*)&g_Wrzf[(size_t)(((16 + cf0 + n) * 16 + ks) * 64 + l) * 8];
      bn[n] = *(const h8*)&g_Wnxf[(size_t)(((cf0 + n) * 8 + ks) * 64 + l) * 8];
    }
#pragma unroll
    for (int n = 0; n < 4; ++n) {
      ar[n] = __builtin_amdgcn_mfma_f32_16x16x32_f16(a, br[n], ar[n], 0, 0, 0);
      az[n] = __builtin_amdgcn_mfma_f32_16x16x32_f16(a, bz[n], az[n], 0, 0, 0);
      ax[n] = __builtin_amdgcn_mfma_f32_16x16x32_f16(a, bn[n], ax[n], 0, 0, 0);
    }
  }

  // ---- h side ----
#pragma unroll
  for (int ks = 0; ks < 8; ++ks) {
    const h8 a = *(const h8*)&aH[ks * 32];
    h8 br[4], bz[4], bn[4];
#pragma unroll
    for (int n = 0; n < 4; ++n) {
      br[n] = *(const h8*)&g_Wrzf[(size_t)(((cf0 + n) * 16 + 8 + ks) * 64 + l) * 8];
      bz[n] = *(const h8*)&g_Wrzf[(size_t)(((16 + cf0 + n) * 16 + 8 + ks) * 64 + l) * 8];
      bn[n] = *(const h8*)&g_Wnhf[(size_t)(((cf0 + n) * 8 + ks) * 64 + l) * 8];
    }
#pragma unroll
    for (int n = 0; n < 4; ++n) {
      ar[n] = __builtin_amdgcn_mfma_f32_16x16x32_f16(a, br[n], ar[n], 0, 0, 0);
      az[n] = __builtin_amdgcn_mfma_f32_16x16x32_f16(a, bz[n], az[n], 0, 0, 0);
      ah[n] = __builtin_amdgcn_mfma_f32_16x16x32_f16(a, bn[n], ah[n], 0, 0, 0);
    }
  }

#pragma unroll
  for (int r = 0; r < 4; ++r) {
    const int node = nb + w * 16 + lg * 4 + r;
    if (node >= NN) continue;
    const float df = (float)(g_rowptr[node + 1] - g_rowptr[node]);
#pragma unroll
    for (int n = 0; n < 4; ++n) {
      const int c = cf * 64 + n * 16 + l15;
      const float rg = 1.f / (1.f + __expf(-(ar[n][r] + df * g_Wib2[c] + b_ih[c] + b_hh[c])));
      const float zg = 1.f / (1.f + __expf(-(az[n][r] + df * g_Wib2[HD + c] + b_ih[HD + c] + b_hh[HD + c])));
      const float u  = ax[n][r] + df * g_Wib2[2 * HD + c] + b_ih[2 * HD + c]
                       + rg * (ah[n][r] + b_hh[2 * HD + c]);
      const float eu = __expf(2.f * fabsf(u));
      const float ng = copysignf(1.f - 2.f / (eu + 1.f), u);
      const float hv = (float)g_hf[(size_t)node * 256 + c];
      out[(size_t)node * HD + c] = (1.f - zg) * ng + zg * hv;
    }
  }
}

extern "C" void kernel_launch(void* const* d_in, const int* in_sizes, int n_in,
                              void* d_out, int out_size, void* d_ws, size_t ws_size,
                              hipStream_t stream)
{
  const float* h     = (const float*)d_in[0];
  const int*   ei    = (const int*)d_in[1];
  const float* eattr = (const float*)d_in[2];
  const float* W1    = (const float*)d_in[3];
  const float* b1    = (const float*)d_in[4];
  const float* W2    = (const float*)d_in[5];
  const float* b2    = (const float*)d_in[6];
  const float* W_ih  = (const float*)d_in[7];
  const float* b_ih  = (const float*)d_in[8];
  const float* W_hh  = (const float*)d_in[9];
  const float* b_hh  = (const float*)d_in[10];
  float* out = (float*)d_out;

  float* S32 = (float*)d_ws;                                // [NN][HD] f32
  int*   deg = (int*)((char*)d_ws + (size_t)NN * HD * 4);   // [NN] i32

  hipMemsetAsync(d_ws, 0, (size_t)NN * HD * 4 + (size_t)NN * 4, stream);
  cvtfold_kernel<<<768 + 168, 256, 0, stream>>>(W1, W_hh, W_ih, W2, b2);
  pre_kernel<<<NN / 32, 256, 0, stream>>>(h, ei, deg);
  scan_kernel<<<1, 512, 0, stream>>>(deg);
  scatter_kernel<<<(NE + 255) / 256, 256, 0, stream>>>(ei);
  aggmsg_kernel<<<NE / 64, 256, 0, stream>>>(eattr, b1, S32);
  node_kernel<<<1252, 256, 0, stream>>>(S32, b_ih, b_hh, out);
}

// Round 14
// 297.873 us; speedup vs baseline: 1.0948x; 1.0948x over previous
//
#include <hip/hip_runtime.h>
#include <math.h>

#define NN 20000     // nodes
#define NE 320000    // edges
#define HD 256       // hidden dim
#define EDIM 64      // edge feature dim
#define DIN 576      // 2H + ED
#define ASTRIDE 264  // LDS row stride in halves

typedef __attribute__((ext_vector_type(4))) _Float16 h4;
typedef __attribute__((ext_vector_type(8))) _Float16 h8;
typedef __attribute__((ext_vector_type(4))) float f32x4;

// fragment order: frag(cf, ks, l, j) = W[cf*16 + (l&15)][ks*32 + (l>>4)*8 + j]
__device__ _Float16 g_W1cf[16 * 2 * 64 * 8];    // W1 eattr part
__device__ _Float16 g_W12f[32 * 8 * 64 * 8];    // [W1a;W1b] for pre kernel (B-operand)
__device__ _Float16 g_Wrzf[32 * 16 * 64 * 8];   // GRU r,z: K=512 = [Wfold | W_hh]
__device__ _Float16 g_Wnxf[16 * 8 * 64 * 8];    // GRU n-gate, S side (Wfold rows 512..767)
__device__ _Float16 g_Wnhf[16 * 8 * 64 * 8];    // GRU n-gate, h side (W_hh rows 512..767)
__device__ float    g_Wib2[768];                // W_ih @ b2
__device__ _Float16 g_pre[(size_t)NN * 512];    // [node][pre1(256) | pre2(256)]
__device__ _Float16 g_hf[(size_t)NN * 256];     // h as fp16
__device__ _Float16 g_S16[(size_t)NN * 256];    // aggregated S, fp16
__device__ _Float16 g_msg[(size_t)NE * 256];    // FINAL hid rows, SORTED by dest
__device__ int      g_rowptr[NN + 1];
__device__ int      g_cursor[NN];

__device__ __forceinline__ h4 f2h4(float4 v) {
  return (h4){(_Float16)v.x, (_Float16)v.y, (_Float16)v.z, (_Float16)v.w};
}
__device__ __forceinline__ h8 f2h8(float4 a, float4 b) {
  return (h8){(_Float16)a.x, (_Float16)a.y, (_Float16)a.z, (_Float16)a.w,
              (_Float16)b.x, (_Float16)b.y, (_Float16)b.z, (_Float16)b.w};
}

// -------------------- merged weight repack + fold --------------------
__global__ __launch_bounds__(256) void cvtfold_kernel(
    const float* __restrict__ W1, const float* __restrict__ W_hh,
    const float* __restrict__ W_ih, const float* __restrict__ W2,
    const float* __restrict__ b2)
{
  const int bid = blockIdx.x;
  if (bid < 768) {
    const int r = bid, c = threadIdx.x;
    const float* wr = W_ih + (size_t)r * HD;
    float acc = 0.f;
    for (int m = 0; m < HD; ++m) acc += wr[m] * W2[(size_t)m * HD + c];
    const int ks = c >> 5, lg = (c >> 3) & 3, j = c & 7;
    const int l = lg * 16 + (r & 15);
    if (r < 512) {
      const int cf = (r < 256) ? (r >> 4) : (16 + ((r - 256) >> 4));
      g_Wrzf[(size_t)((cf * 16 + ks) * 64 + l) * 8 + j] = (_Float16)acc;
    } else {
      const int cf = (r - 512) >> 4;
      g_Wnxf[(size_t)((cf * 8 + ks) * 64 + l) * 8 + j] = (_Float16)acc;
    }
    if (c == 0) {
      float a2 = 0.f;
      for (int m = 0; m < HD; ++m) a2 += wr[m] * b2[m];
      g_Wib2[r] = a2;
    }
    return;
  }
  const int idx = (bid - 768) * 256 + threadIdx.x;
  const int g = idx >> 6, l = idx & 63;
  const int r16 = l & 15, koff = (l >> 4) * 8;
  const float* src; _Float16* dst;
  if (g < 32) {                                   // W1cf: cf<16, ks<2 (k = 512+...)
    const int cf = g >> 1, ks = g & 1;
    src = &W1[(size_t)(cf * 16 + r16) * DIN + 512 + ks * 32 + koff];
    dst = &g_W1cf[(size_t)(cf * 2 + ks) * 512 + l * 8];
  } else if (g < 288) {                           // W12f: cf<32, ks<8
    const int gg = g - 32, cf = gg >> 3, ks = gg & 7;
    src = (cf < 16) ? &W1[(size_t)(cf * 16 + r16) * DIN + ks * 32 + koff]
                    : &W1[(size_t)((cf - 16) * 16 + r16) * DIN + 256 + ks * 32 + koff];
    dst = &g_W12f[(size_t)(cf * 8 + ks) * 512 + l * 8];
  } else if (g < 544) {                           // Wrzf ks in [8,16): W_hh r,z rows
    const int gg = g - 288, cf = gg >> 3, ks = 8 + (gg & 7);
    const int row = (cf < 16) ? cf * 16 + r16 : 256 + (cf - 16) * 16 + r16;
    src = &W_hh[(size_t)row * HD + (ks - 8) * 32 + koff];
    dst = &g_Wrzf[(size_t)(cf * 16 + ks) * 512 + l * 8];
  } else {                                        // Wnhf: W_hh rows 512..767
    const int gg = g - 544, cf = gg >> 3, ks = gg & 7;
    src = &W_hh[(size_t)(512 + cf * 16 + r16) * HD + ks * 32 + koff];
    dst = &g_Wnhf[(size_t)(cf * 8 + ks) * 512 + l * 8];
  }
#pragma unroll
  for (int j = 0; j < 8; ++j) dst[j] = (_Float16)src[j];
}

// -------------------- pre kernel (+ edge histogram): pre12 = h @ [W1a|W1b]^T ----
#define PSTR 264
__global__ __launch_bounds__(256, 4) void pre_kernel(const float* __restrict__ h,
                                                     const int* __restrict__ ei,
                                                     int* __restrict__ deg) {
  __shared__ _Float16 A[32 * PSTR];   // 16.9 KB
  const int t = threadIdx.x, w = t >> 6, l = t & 63;
  const int l15 = l & 15, lg = l >> 4;
  const int nb = blockIdx.x * 32;

  {
    const int gid = blockIdx.x * 256 + t;
    atomicAdd(&deg[ei[gid]], 1);
    atomicAdd(&deg[ei[gid + NE / 2]], 1);
  }

  const int row = t >> 3, c8 = t & 7;
#pragma unroll
  for (int i = 0; i < 8; ++i) {
    const int col4 = c8 + i * 8;
    float4 v = ((const float4*)(h + (size_t)(nb + row) * HD))[col4];
    const h4 x = f2h4(v);
    *(h4*)&A[row * PSTR + col4 * 4] = x;
    *(h4*)&g_hf[(size_t)(nb + row) * 256 + col4 * 4] = x;
  }
  __syncthreads();

  f32x4 acc[2][8];
#pragma unroll
  for (int m = 0; m < 2; ++m)
#pragma unroll
    for (int n = 0; n < 8; ++n) acc[m][n] = (f32x4){0.f, 0.f, 0.f, 0.f};

  for (int ks = 0; ks < 8; ++ks) {
    h8 a[2];
#pragma unroll
    for (int m = 0; m < 2; ++m)
      a[m] = *(const h8*)&A[(m * 16 + l15) * PSTR + ks * 32 + lg * 8];
#pragma unroll
    for (int n = 0; n < 8; ++n) {
      const h8 b = *(const h8*)&g_W12f[(size_t)((w * 8 + n) * 8 + ks) * 512 + l * 8];
#pragma unroll
      for (int m = 0; m < 2; ++m)
        acc[m][n] = __builtin_amdgcn_mfma_f32_16x16x32_f16(a[m], b, acc[m][n], 0, 0, 0);
    }
  }

#pragma unroll
  for (int m = 0; m < 2; ++m)
#pragma unroll
    for (int n = 0; n < 8; ++n) {
      const int col = w * 128 + n * 16 + l15;
#pragma unroll
      for (int r = 0; r < 4; ++r)
        g_pre[(size_t)(nb + m * 16 + lg * 4 + r) * 512 + col] = (_Float16)acc[m][n][r];
    }
}

// -------------------- CSR build: scan (rowptr + cursor init) --------------------
__global__ __launch_bounds__(512) void scan_kernel(const int* __restrict__ deg) {
  __shared__ int part[512];
  const int t = threadIdx.x;
  const int base = t * 40;
  int loc[40];
  int s = 0;
#pragma unroll
  for (int i = 0; i < 40; ++i) {
    const int idx = base + i;
    const int d = (idx < NN) ? deg[idx] : 0;
    loc[i] = s; s += d;
  }
  part[t] = s;
  __syncthreads();
  for (int off = 1; off < 512; off <<= 1) {
    const int v = (t >= off) ? part[t - off] : 0;
    __syncthreads();
    part[t] += v;
    __syncthreads();
  }
  const int pre = (t == 0) ? 0 : part[t - 1];
#pragma unroll
  for (int i = 0; i < 40; ++i) {
    const int idx = base + i;
    if (idx < NN) { const int v = pre + loc[i]; g_rowptr[idx] = v; g_cursor[idx] = v; }
  }
  if (t == 511) g_rowptr[NN] = part[511];
}

// -------------------- msg kernel: eattr GEMM -> transpose -> fold+relu -> sorted ----
// Sequential eattr read (edge order). Inline cursor atomic gives the sorted slot.
// Post-transpose: add pre1[dest]+pre2[src]+b1 as COALESCED h4 row reads, ReLU,
// store final hid row (512B burst) to its sorted position. g_msg = final hid.
__global__ __launch_bounds__(256, 4) void msg_kernel(const float* __restrict__ eattr,
                                                     const int* __restrict__ ei,
                                                     const float* __restrict__ b1) {
  __shared__ _Float16 T[64 * ASTRIDE];   // 33.8 KB
  __shared__ int pL[64];
  const int t = threadIdx.x, w = t >> 6, l = t & 63;
  const int l15 = l & 15, lg = l >> 4;
  const int e0 = blockIdx.x * 64;

  if (t < 64) pL[t] = atomicAdd(&g_cursor[ei[e0 + t]], 1);

  f32x4 acc[4][4];
#pragma unroll
  for (int m = 0; m < 4; ++m)
#pragma unroll
    for (int n = 0; n < 4; ++n) acc[m][n] = (f32x4){0.f, 0.f, 0.f, 0.f};

#pragma unroll
  for (int ks = 0; ks < 2; ++ks) {
    h8 a[4], b[4];
#pragma unroll
    for (int m = 0; m < 4; ++m) {
      const float* ep = eattr + (size_t)(e0 + m * 16 + l15) * EDIM + ks * 32 + lg * 8;
      a[m] = f2h8(((const float4*)ep)[0], ((const float4*)ep)[1]);
    }
#pragma unroll
    for (int n = 0; n < 4; ++n)
      b[n] = *(const h8*)&g_W1cf[(size_t)((w * 4 + n) * 2 + ks) * 512 + l * 8];
#pragma unroll
    for (int m = 0; m < 4; ++m)
#pragma unroll
      for (int n = 0; n < 4; ++n)
        acc[m][n] = __builtin_amdgcn_mfma_f32_16x16x32_f16(a[m], b[n], acc[m][n], 0, 0, 0);
  }

#pragma unroll
  for (int m = 0; m < 4; ++m)
#pragma unroll
    for (int n = 0; n < 4; ++n)
#pragma unroll
      for (int r = 0; r < 4; ++r)
        T[(m * 16 + lg * 4 + r) * ASTRIDE + w * 64 + n * 16 + l15] = (_Float16)acc[m][n][r];
  __syncthreads();   // also publishes pL

  const f32x4 b1v = *(const f32x4*)&b1[l * 4];
#pragma unroll
  for (int i = 0; i < 16; ++i) {
    const int e = w * 16 + i;
    const int ge = e0 + e;
    const int dest = ei[ge];             // wave-uniform scalar loads
    const int srcn = ei[NE + ge];
    const h4 tt = *(const h4*)&T[e * ASTRIDE + l * 4];
    const h4 q1 = *(const h4*)&g_pre[(size_t)dest * 512 + l * 4];
    const h4 q2 = *(const h4*)&g_pre[(size_t)srcn * 512 + 256 + l * 4];
    h4 o;
#pragma unroll
    for (int r = 0; r < 4; ++r) {
      float x = (float)tt[r] + (float)q1[r] + (float)q2[r] + b1v[r];
      o[r] = (_Float16)(x > 0.f ? x : 0.f);
    }
    *(h4*)&g_msg[(size_t)pL[e] * 256 + l * 4] = o;
  }
}

// -------------------- agg kernel: pure sequential segmented sum -> fp16 S ----
__global__ __launch_bounds__(256) void agg_kernel() {
  const int t = threadIdx.x, w = t >> 6, l = t & 63;
  const int n = blockIdx.x * 4 + w;
  const int start = g_rowptr[n];
  const int end = g_rowptr[n + 1];

  f32x4 acc = (f32x4){0.f, 0.f, 0.f, 0.f};
  int p = start;
  for (; p + 4 <= end; p += 4) {
    h4 m[4];
#pragma unroll
    for (int k = 0; k < 4; ++k)
      m[k] = *(const h4*)&g_msg[(size_t)(p + k) * 256 + l * 4];
#pragma unroll
    for (int k = 0; k < 4; ++k)
#pragma unroll
      for (int r = 0; r < 4; ++r) acc[r] += (float)m[k][r];
  }
  for (; p < end; ++p) {
    const h4 m0 = *(const h4*)&g_msg[(size_t)p * 256 + l * 4];
#pragma unroll
    for (int r = 0; r < 4; ++r) acc[r] += (float)m0[r];
  }
  *(h4*)&g_S16[(size_t)n * 256 + l * 4] =
      (h4){(_Float16)acc[0], (_Float16)acc[1], (_Float16)acc[2], (_Float16)acc[3]};
}

// -------------------- node kernel: LDS-free, barrier-free streaming GEMM ----
__global__ __launch_bounds__(256, 2) void node_kernel(
    const float* __restrict__ b_ih, const float* __restrict__ b_hh,
    float* __restrict__ out)
{
  const int bid = blockIdx.x;
  const int cf = bid & 3, rng = bid >> 2;
  const int t = threadIdx.x, w = t >> 6, l = t & 63;
  const int l15 = l & 15, lg = l >> 4;
  const int nb = rng * 64;
  const int cf0 = cf * 4;
  int na = nb + w * 16 + l15; if (na >= NN) na = NN - 1;

  f32x4 ar[4], az[4], ax[4], ah[4];
#pragma unroll
  for (int n = 0; n < 4; ++n) {
    ar[n] = (f32x4){0.f, 0.f, 0.f, 0.f}; az[n] = (f32x4){0.f, 0.f, 0.f, 0.f};
    ax[n] = (f32x4){0.f, 0.f, 0.f, 0.f}; ah[n] = (f32x4){0.f, 0.f, 0.f, 0.f};
  }

  const _Float16* aS = &g_S16[(size_t)na * 256 + lg * 8];
  const _Float16* aH = &g_hf[(size_t)na * 256 + lg * 8];

  // ---- S side: r,z (ksg = ks) + n-gate x side ----
#pragma unroll
  for (int ks = 0; ks < 8; ++ks) {
    const h8 a = *(const h8*)&aS[ks * 32];
    h8 br[4], bz[4], bn[4];
#pragma unroll
    for (int n = 0; n < 4; ++n) {
      br[n] = *(const h8*)&g_Wrzf[(size_t)(((cf0 + n) * 16 + ks) * 64 + l) * 8];
      bz[n] = *(const h8*)&g_Wrzf[(size_t)(((16 + cf0 + n) * 16 + ks) * 64 + l) * 8];
      bn[n] = *(const h8*)&g_Wnxf[(size_t)(((cf0 + n) * 8 + ks) * 64 + l) * 8];
    }
#pragma unroll
    for (int n = 0; n < 4; ++n) {
      ar[n] = __builtin_amdgcn_mfma_f32_16x16x32_f16(a, br[n], ar[n], 0, 0, 0);
      az[n] = __builtin_amdgcn_mfma_f32_16x16x32_f16(a, bz[n], az[n], 0, 0, 0);
      ax[n] = __builtin_amdgcn_mfma_f32_16x16x32_f16(a, bn[n], ax[n], 0, 0, 0);
    }
  }

  // ---- h side: r,z (ksg = 8+ks) + n-gate h side ----
#pragma unroll
  for (int ks = 0; ks < 8; ++ks) {
    const h8 a = *(const h8*)&aH[ks * 32];
    h8 br[4], bz[4], bn[4];
#pragma unroll
    for (int n = 0; n < 4; ++n) {
      br[n] = *(const h8*)&g_Wrzf[(size_t)(((cf0 + n) * 16 + 8 + ks) * 64 + l) * 8];
      bz[n] = *(const h8*)&g_Wrzf[(size_t)(((16 + cf0 + n) * 16 + 8 + ks) * 64 + l) * 8];
      bn[n] = *(const h8*)&g_Wnhf[(size_t)(((cf0 + n) * 8 + ks) * 64 + l) * 8];
    }
#pragma unroll
    for (int n = 0; n < 4; ++n) {
      ar[n] = __builtin_amdgcn_mfma_f32_16x16x32_f16(a, br[n], ar[n], 0, 0, 0);
      az[n] = __builtin_amdgcn_mfma_f32_16x16x32_f16(a, bz[n], az[n], 0, 0, 0);
      ah[n] = __builtin_amdgcn_mfma_f32_16x16x32_f16(a, bn[n], ah[n], 0, 0, 0);
    }
  }

#pragma unroll
  for (int r = 0; r < 4; ++r) {
    const int node = nb + w * 16 + lg * 4 + r;
    if (node >= NN) continue;
    const float df = (float)(g_rowptr[node + 1] - g_rowptr[node]);
#pragma unroll
    for (int n = 0; n < 4; ++n) {
      const int c = cf * 64 + n * 16 + l15;
      const float rg = 1.f / (1.f + __expf(-(ar[n][r] + df * g_Wib2[c] + b_ih[c] + b_hh[c])));
      const float zg = 1.f / (1.f + __expf(-(az[n][r] + df * g_Wib2[HD + c] + b_ih[HD + c] + b_hh[HD + c])));
      const float u  = ax[n][r] + df * g_Wib2[2 * HD + c] + b_ih[2 * HD + c]
                       + rg * (ah[n][r] + b_hh[2 * HD + c]);
      const float eu = __expf(2.f * fabsf(u));
      const float ng = copysignf(1.f - 2.f / (eu + 1.f), u);
      const float hv = (float)g_hf[(size_t)node * 256 + c];
      out[(size_t)node * HD + c] = (1.f - zg) * ng + zg * hv;
    }
  }
}

extern "C" void kernel_launch(void* const* d_in, const int* in_sizes, int n_in,
                              void* d_out, int out_size, void* d_ws, size_t ws_size,
                              hipStream_t stream)
{
  const float* h     = (const float*)d_in[0];
  const int*   ei    = (const int*)d_in[1];
  const float* eattr = (const float*)d_in[2];
  const float* W1    = (const float*)d_in[3];
  const float* b1    = (const float*)d_in[4];
  const float* W2    = (const float*)d_in[5];
  const float* b2    = (const float*)d_in[6];
  const float* W_ih  = (const float*)d_in[7];
  const float* b_ih  = (const float*)d_in[8];
  const float* W_hh  = (const float*)d_in[9];
  const float* b_hh  = (const float*)d_in[10];
  float* out = (float*)d_out;

  int* deg = (int*)d_ws;   // [NN] i32

  hipMemsetAsync(deg, 0, (size_t)NN * 4, stream);
  cvtfold_kernel<<<768 + 168, 256, 0, stream>>>(W1, W_hh, W_ih, W2, b2);
  pre_kernel<<<NN / 32, 256, 0, stream>>>(h, ei, deg);
  scan_kernel<<<1, 512, 0, stream>>>(deg);
  msg_kernel<<<NE / 64, 256, 0, stream>>>(eattr, ei, b1);
  agg_kernel<<<NN / 4, 256, 0, stream>>>();
  node_kernel<<<1252, 256, 0, stream>>>(b_ih, b_hh, out);
}